// Round 10
// baseline (261.170 us; speedup 1.0000x reference)
//
#include <hip/hip_runtime.h>
#include <hip/hip_bf16.h>

// B=32, N=4096, P=256, L=16, DR=128, H=128, NUM_REL=400.
// Contract (verified r5-r9): float inputs f32, ints int32, output f32 [32][128].
// r10: fix the r9 regression — __launch_bounds__(512,2) capped VGPR at 128 so
// the 128-reg resident-W file silently became per-step global reloads
// (VGPR_Count=124, MfmaUtil 8%). Now (512,1): 8 waves/CU, 256-VGPR budget,
// W truly resident; rel gathers hoisted before the MFMA loop. Tail: prep
// split into transpose+repack+sort+qk (k_prep1) and coalesced relproj
// (k_prep2); k_attn uses precomputed qk.

#define B_    32
#define N_    4096
#define L_    16
#define DR_   128
#define H_    128
#define G4_   512
#define AST2  264        // A row stride in bf16 elems (528B, 16B-aligned)
#define NPATH 8192
#define NPB   32

typedef unsigned short bfraw;
typedef short short8 __attribute__((ext_vector_type(8)));
typedef float f32x4 __attribute__((ext_vector_type(4)));

__device__ int   g_isbf16;
__device__ int   g_isi64;
__device__ __align__(16) bfraw g_Wcat[G4_ * 256];    // [n][k] bf16, 256KB
__device__ __align__(16) float g_WihT[DR_ * G4_];    // [d][n] = W_ih[n][128+d], f32
__device__ float g_relproj[400 * G4_];               // [400][512] f32
__device__ float g_bias[G4_];
__device__ float g_qk[B_ * H_];                      // Wk^T q per batch
__device__ float g_qbk[B_];                          // q . bk per batch
__device__ int   g_perm[NPATH];
__device__ float g_last[NPATH * H_];                 // f32 [8192][128]

__device__ __forceinline__ float bfc(bfraw v) {
    return __uint_as_float(((unsigned)v) << 16);
}
__device__ __forceinline__ bfraw f2b(float f) {      // RNE f32->bf16
    unsigned u = __float_as_uint(f);
    return (bfraw)((u + 0x7FFFu + ((u >> 16) & 1u)) >> 16);
}
__device__ __forceinline__ unsigned pk2(float a, float b) {
    return (unsigned)f2b(a) | ((unsigned)f2b(b) << 16);
}
__device__ __forceinline__ float ld(const void* p, size_t i, int isbf) {
    return isbf ? bfc(((const bfraw*)p)[i]) : ((const float*)p)[i];
}
__device__ __forceinline__ float sigf(float x) { return 1.0f / (1.0f + __expf(-x)); }
__device__ __forceinline__ float tanhfast(float x) { return 2.0f * sigf(2.0f * x) - 1.0f; }

__device__ __forceinline__ float dot128(const float* __restrict__ w,
                                        const float* __restrict__ s) {
    float acc = 0.f;
    #pragma unroll
    for (int i = 0; i < 32; ++i) {
        const float4 wv = *(const float4*)(w + i * 4);
        acc = fmaf(wv.x, s[i*4+0], fmaf(wv.y, s[i*4+1],
              fmaf(wv.z, s[i*4+2], fmaf(wv.w, s[i*4+3], acc))));
    }
    return acc;
}

// ---------------------------------------------------------------------------
// k_prep1, grid 417 x 512:
//   blocks 0..127   : g_WihT[d][n] = W_ih[n][128+d]  (d = blk)
//   blocks 128..383 : W repack -> g_Wcat bf16
//   block  384      : flags + bias + counting sort
//   blocks 385..416 : q = Wq.node_opt[b]+bq; g_qk[b]=Wk^T q; g_qbk[b]=q.bk
// Every block re-detects dtypes locally (no cross-block dependency).
__global__ __launch_bounds__(512) void k_prep1(
    const void* __restrict__ node_opt, const int* __restrict__ node_idx,
    const void* __restrict__ W_ih, const void* __restrict__ W_hh,
    const void* __restrict__ b_ih, const void* __restrict__ b_hh,
    const void* __restrict__ in_proj_w, const void* __restrict__ in_proj_b,
    const int* __restrict__ path_lens)
{
    __shared__ int s_big, s_nz, hist[16], cur[16];
    __shared__ float q[128];
    const int tid = threadIdx.x;
    const int blk = blockIdx.x;

    if (tid == 0) { s_big = 0; s_nz = 0; }
    __syncthreads();
    {
        const unsigned short* u = (const unsigned short*)node_opt;
        int big = 0;
        #pragma unroll
        for (int i = 0; i < 4; ++i) {
            const float v = fabsf(bfc(u[tid + i * 512]));
            big |= !(v < 1.0e3f);             // NaN-safe
        }
        if (big) s_big = 1;
        if (node_idx[2 * tid + 1] != 0) s_nz = 1;
    }
    __syncthreads();
    const int isbf = s_big ? 0 : 1;
    const int i64  = s_nz ? 0 : 1;

    if (blk < 128) {
        const int d = blk, n = tid;
        g_WihT[d * G4_ + n] = ld(W_ih, (size_t)n * 256 + 128 + d, isbf);
    } else if (blk < 384) {
        const int idx = (blk - 128) * 512 + tid;   // 0..131071
        const int n = idx >> 8, k = idx & 255;
        const float v = (k < H_) ? ld(W_hh, (size_t)n * H_ + k, isbf)
                                 : ld(W_ih, (size_t)n * 256 + (k - H_), isbf);
        g_Wcat[n * 256 + k] = f2b(v);
    } else if (blk == 384) {
        if (tid == 0) { g_isbf16 = isbf; g_isi64 = i64; }
        g_bias[tid] = ld(b_ih, tid, isbf) + ld(b_hh, tid, isbf);
        if (tid < 16) hist[tid] = 0;
        __syncthreads();
        for (int p = tid; p < NPATH; p += 512) {
            const int len = i64 ? path_lens[2 * p] : path_lens[p];
            atomicAdd(&hist[len - 1], 1);
        }
        __syncthreads();
        if (tid == 0) {
            int off = 0;
            for (int b = 15; b >= 0; --b) { cur[b] = off; off += hist[b]; }
        }
        __syncthreads();
        for (int p = tid; p < NPATH; p += 512) {
            const int len = i64 ? path_lens[2 * p] : path_lens[p];
            const int pos = atomicAdd(&cur[len - 1], 1);
            g_perm[pos] = p;
        }
    } else {
        const int b = blk - 385;          // 0..31
        if (tid < 128) {
            float s = 0.f;
            for (int j = 0; j < 128; ++j)
                s = fmaf(ld(node_opt, b * 128 + j, isbf),
                         ld(in_proj_w, (size_t)tid * 128 + j, isbf), s);
            q[tid] = s + ld(in_proj_b, tid, isbf);
        }
        __syncthreads();
        if (tid < 128) {                  // qk[u] = sum_j q[j]*Wk[j][u]
            float s = 0.f;
            for (int j = 0; j < 128; ++j)
                s = fmaf(q[j], ld(in_proj_w, (size_t)(128 + j) * 128 + tid, isbf), s);
            g_qk[b * 128 + tid] = s;
        } else if (tid == 128) {
            float s = 0.f;
            for (int j = 0; j < 128; ++j)
                s = fmaf(q[j], ld(in_proj_b, 128 + j, isbf), s);
            g_qbk[b] = s;
        }
    }
}

// ---------------------------------------------------------------------------
// k_prep2: rel_proj[r][n] = sum_d rel_embeds[r][d] * g_WihT[d][n]  (coalesced)
__global__ __launch_bounds__(512) void k_prep2(const void* __restrict__ rel_embeds)
{
    __shared__ float relv[DR_];
    const int isbf = g_isbf16;
    const int r = blockIdx.x;          // 0..399
    const int n = threadIdx.x;         // 0..511
    if (n < DR_) relv[n] = ld(rel_embeds, (size_t)r * DR_ + n, isbf);
    __syncthreads();
    float s = 0.f;
    #pragma unroll 4
    for (int d = 0; d < DR_; ++d)
        s = fmaf(relv[d], g_WihT[d * G4_ + n], s);
    g_relproj[r * G4_ + n] = s;
}

// ---------------------------------------------------------------------------
// MFMA LSTM: 256 blocks x 512 threads (8 waves = 1 block/CU), NPB=32,
// N=512, K=256. W fragments resident in 128 VGPRs/lane (launch_bounds(512,1)
// -> 256-VGPR budget at 2 waves/SIMD). Per step: commit x -> barrier ->
// rel gathers + x prefetch + ds_read/MFMA -> barrier -> epilogue.
__global__ __launch_bounds__(512, 1) void k_lstm(
    const void* __restrict__ graph_embed,   // [32][4096][128] f32 (or bf16)
    const int*  __restrict__ node_idx,      // [8192][16]
    const int*  __restrict__ rel_idx,       // [8192][16]
    const int*  __restrict__ path_lens)     // [8192]
{
    __shared__ __align__(16) bfraw A[NPB][AST2];    // [path][ h(0:128) | node(128:256) ]
    __shared__ int s_pid[NPB], s_len[NPB];
    __shared__ int s_nid[NPB][L_], s_rid[NPB][L_];

    const int isbf = g_isbf16;
    const int i64  = g_isi64;
    const int tid  = threadIdx.x;

    if (tid < NPB) {
        const int pid = g_perm[blockIdx.x * NPB + tid];
        s_pid[tid] = pid;
        s_len[tid] = i64 ? path_lens[2 * pid] : path_lens[pid];
    }
    __syncthreads();
    {   // indices: 512 threads = 32 paths x 16 steps
        const int m = tid >> 4, t = tid & 15;
        const int idx = s_pid[m] * L_ + t;
        s_nid[m][t] = i64 ? node_idx[2 * idx] : node_idx[idx];
        s_rid[m][t] = i64 ? rel_idx[2 * idx]  : rel_idx[idx];
    }
    {   // zero h region (k<128)
        const int m = tid >> 4, i0 = (tid & 15) * 8;
        *(uint4*)&A[m][i0] = make_uint4(0, 0, 0, 0);
    }
    __syncthreads();

    int maxlen = 0;
    #pragma unroll
    for (int m = 0; m < NPB; ++m) maxlen = max(maxlen, s_len[m]);

    const int w    = tid >> 6;     // wave 0..7
    const int l    = tid & 63;
    const int quad = l >> 4;
    const int col  = l & 15;
    const int u0   = w * 16 + col; // owned unit

    // ---- resident W fragments: wreg[ck][g] = W[g*128+u0][ck*32+quad*8 ..+8] ----
    short8 wreg[8][4];
    float bq4[4];
    #pragma unroll
    for (int g = 0; g < 4; ++g) {
        bq4[g] = g_bias[g * 128 + u0];
        const bfraw* wrow = g_Wcat + (size_t)(g * 128 + u0) * 256 + quad * 8;
        #pragma unroll
        for (int ck = 0; ck < 8; ++ck)
            wreg[ck][g] = *(const short8*)(wrow + ck * 32);
    }

    // x-gather prefetch (thread pm stages 8 node elems at pi0)
    const int pm  = tid >> 4;
    const int pi0 = (tid & 15) * 8;
    const size_t gbase = (size_t)(s_pid[pm] >> 8) * (size_t)(N_ * DR_);
    uint4 pn0, pn1;
    {
        const int nid = s_nid[pm][0];
        if (isbf) {
            pn0 = *(const uint4*)((const bfraw*)graph_embed + gbase + (size_t)nid * DR_ + pi0);
        } else {
            const float* gp = (const float*)graph_embed + gbase + (size_t)nid * DR_ + pi0;
            pn0 = *(const uint4*)gp; pn1 = *(const uint4*)(gp + 4);
        }
    }

    float c[2][4];
    #pragma unroll
    for (int mt = 0; mt < 2; ++mt)
        #pragma unroll
        for (int r = 0; r < 4; ++r) c[mt][r] = 0.f;

    for (int t = 0; t < maxlen; ++t) {
        // ---- commit prefetched node x(t) into A (masked) ----
        {
            uint4 npk = make_uint4(0, 0, 0, 0);
            if (t < s_len[pm]) {
                if (isbf) npk = pn0;
                else {
                    const float* a = (const float*)&pn0;
                    const float* b = (const float*)&pn1;
                    npk = make_uint4(pk2(a[0],a[1]), pk2(a[2],a[3]),
                                     pk2(b[0],b[1]), pk2(b[2],b[3]));
                }
            }
            *(uint4*)&A[pm][128 + pi0] = npk;
        }
        __syncthreads();                 // x(t) + h(t-1) visible

        // ---- rel_proj gathers FIRST (latency overlaps MFMA below) ----
        float rl[2][4][4];
        #pragma unroll
        for (int mt = 0; mt < 2; ++mt)
            #pragma unroll
            for (int r = 0; r < 4; ++r) {
                const int m = mt * 16 + quad * 4 + r;
                const float* rp = g_relproj + (size_t)s_rid[m][t] * G4_ + u0;
                #pragma unroll
                for (int g = 0; g < 4; ++g) rl[mt][g][r] = rp[g * 128];
            }
        // ---- x prefetch for t+1 (block-uniform branch) ----
        if (t + 1 < maxlen) {
            const int nid = s_nid[pm][t + 1];
            if (isbf) {
                pn0 = *(const uint4*)((const bfraw*)graph_embed + gbase + (size_t)nid * DR_ + pi0);
            } else {
                const float* gp = (const float*)graph_embed + gbase + (size_t)nid * DR_ + pi0;
                pn0 = *(const uint4*)gp; pn1 = *(const uint4*)(gp + 4);
            }
        }

        // ---- MFMA K-loop: A from LDS, W from registers ----
        f32x4 acc[2][4];
        #pragma unroll
        for (int mt = 0; mt < 2; ++mt)
            #pragma unroll
            for (int g = 0; g < 4; ++g) {
                const float b = bq4[g];
                acc[mt][g][0] = b; acc[mt][g][1] = b;
                acc[mt][g][2] = b; acc[mt][g][3] = b;
            }
        #pragma unroll
        for (int ck = 0; ck < 8; ++ck) {
            const short8 a0 = *(const short8*)&A[col][ck * 32 + quad * 8];
            const short8 a1 = *(const short8*)&A[16 + col][ck * 32 + quad * 8];
            #pragma unroll
            for (int g = 0; g < 4; ++g) {
                acc[0][g] = __builtin_amdgcn_mfma_f32_16x16x32_bf16(a0, wreg[ck][g], acc[0][g], 0, 0, 0);
                acc[1][g] = __builtin_amdgcn_mfma_f32_16x16x32_bf16(a1, wreg[ck][g], acc[1][g], 0, 0, 0);
            }
        }
        __syncthreads();                 // all A reads done before h overwrite

        // ---- gates + cell update + h write + snapshot ----
        #pragma unroll
        for (int mt = 0; mt < 2; ++mt)
            #pragma unroll
            for (int r = 0; r < 4; ++r) {
                const int m = mt * 16 + quad * 4 + r;
                const float relm = (t < s_len[m] - 1) ? 1.0f : 0.0f;
                const float ig = sigf(acc[mt][0][r] + relm * rl[mt][0][r]);
                const float fg = sigf(acc[mt][1][r] + relm * rl[mt][1][r]);
                const float gg = tanhfast(acc[mt][2][r] + relm * rl[mt][2][r]);
                const float og = sigf(acc[mt][3][r] + relm * rl[mt][3][r]);
                const float cc = fg * c[mt][r] + ig * gg;
                c[mt][r] = cc;
                const float h = og * tanhfast(cc);
                A[m][u0] = f2b(h);
                if (t == s_len[m] - 1)
                    g_last[(size_t)s_pid[m] * H_ + u0] = h;
            }
    }
}

// ---------------------------------------------------------------------------
// Attention epilogue (qk precomputed in k_prep1), one block per batch elem.
__global__ __launch_bounds__(256) void k_attn(
    const void* __restrict__ in_proj_w,   // [384][128]
    const void* __restrict__ in_proj_b,   // [384]
    const void* __restrict__ out_proj_w,  // [128][128]
    const void* __restrict__ out_proj_b,  // [128]
    float* __restrict__ out)              // [32][128] f32
{
    const int isbf = g_isbf16;
    const int b = blockIdx.x, tid = threadIdx.x;
    __shared__ __align__(16) float qk[128], sv2[2][128], ctx[128], sv[128];
    __shared__ float logits[256];
    __shared__ float red[12];

    if (tid < 128) qk[tid] = g_qk[b * 128 + tid];
    __syncthreads();
    {   // logit for path p = tid
        const float* lp = g_last + ((size_t)b * 256 + tid) * H_;
        const float s = dot128(lp, qk);
        logits[tid] = (s + g_qbk[b]) * 0.08838834764831845f;  // 1/sqrt(128)
    }
    __syncthreads();
    float v = logits[tid];
    #pragma unroll
    for (int off = 32; off > 0; off >>= 1) v = fmaxf(v, __shfl_xor(v, off, 64));
    if ((tid & 63) == 0) red[tid >> 6] = v;
    __syncthreads();
    if (tid == 0) red[8] = fmaxf(fmaxf(red[0], red[1]), fmaxf(red[2], red[3]));
    __syncthreads();
    const float e = __expf(logits[tid] - red[8]);
    float sum = e;
    #pragma unroll
    for (int off = 32; off > 0; off >>= 1) sum += __shfl_xor(sum, off, 64);
    if ((tid & 63) == 0) red[4 + (tid >> 6)] = sum;
    __syncthreads();
    if (tid == 0) red[9] = red[4] + red[5] + red[6] + red[7];
    __syncthreads();
    logits[tid] = e / red[9];
    __syncthreads();
    {   // sv[u] = sum_p attn[p] * last[b,p,u]
        const int u = tid & 127, half = tid >> 7;
        float s = 0.f;
        const float* lb = g_last + ((size_t)b * 256 + half * 128) * H_ + u;
        for (int p = 0; p < 128; ++p)
            s = fmaf(logits[half * 128 + p], lb[(size_t)p * H_], s);
        sv2[half][u] = s;
    }
    __syncthreads();
    if (tid < 128) sv[tid] = sv2[0][tid] + sv2[1][tid];
    __syncthreads();
    if (tid < 128) {
        float s;
        if (isbf) {
            s = 0.f;
            for (int u = 0; u < 128; ++u)
                s = fmaf(sv[u], ld(in_proj_w, (size_t)(256 + tid) * 128 + u, 1), s);
        } else {
            s = dot128((const float*)in_proj_w + (size_t)(256 + tid) * 128, sv);
        }
        ctx[tid] = s + ld(in_proj_b, 256 + tid, isbf);
    }
    __syncthreads();
    if (tid < 128) {
        float s;
        if (isbf) {
            s = 0.f;
            for (int d = 0; d < 128; ++d)
                s = fmaf(ctx[d], ld(out_proj_w, (size_t)tid * 128 + d, 1), s);
        } else {
            s = dot128((const float*)out_proj_w + (size_t)tid * 128, ctx);
        }
        out[b * 128 + tid] = s + ld(out_proj_b, tid, isbf);
    }
}

// ---------------------------------------------------------------------------
extern "C" void kernel_launch(void* const* d_in, const int* in_sizes, int n_in,
                              void* d_out, int out_size, void* d_ws, size_t ws_size,
                              hipStream_t stream)
{
    const void* graph_embed = d_in[0];
    const void* node_opt    = d_in[1];
    const void* rel_embeds  = d_in[2];
    const void* W_ih        = d_in[3];
    const void* W_hh        = d_in[4];
    const void* b_ih        = d_in[5];
    const void* b_hh        = d_in[6];
    const void* in_proj_w   = d_in[7];
    const void* in_proj_b   = d_in[8];
    const void* out_proj_w  = d_in[9];
    const void* out_proj_b  = d_in[10];
    const int* node_idx  = (const int*)d_in[11];
    const int* rel_idx   = (const int*)d_in[12];
    const int* path_lens = (const int*)d_in[13];
    (void)d_ws; (void)ws_size; (void)in_sizes; (void)n_in; (void)out_size;

    hipLaunchKernelGGL(k_prep1, dim3(417), dim3(512), 0, stream,
                       node_opt, node_idx, W_ih, W_hh, b_ih, b_hh,
                       in_proj_w, in_proj_b, path_lens);
    hipLaunchKernelGGL(k_prep2, dim3(400), dim3(512), 0, stream, rel_embeds);
    hipLaunchKernelGGL(k_lstm, dim3(NPATH / NPB), dim3(512), 0, stream,
                       graph_embed, node_idx, rel_idx, path_lens);
    hipLaunchKernelGGL(k_attn, dim3(B_), dim3(256), 0, stream,
                       in_proj_w, in_proj_b, out_proj_w, out_proj_b,
                       (float*)d_out);
}